// Round 1
// baseline (990.184 us; speedup 1.0000x reference)
//
#include <hip/hip_runtime.h>
#include <math.h>

// Problem constants
#define NN 8
#define CC 256
#define LL 1024
#define EE 512
#define HEADS 8
#define DH 64

// Workspace float offsets
#define OFF_STYLE   0u          // 8*256            = 2048
#define OFF_WQ      2048u       // 1536*256         = 393216
#define OFF_BIAS    395264u     // 1536
#define OFF_WP      396800u     // 256*512          = 131072
#define OFF_COS     527872u     // 1024*32          = 32768
#define OFF_SIN     560640u     // 1024*32          = 32768
#define OFF_Q       593408u     // 8*8*1024*64      = 4194304
#define OFF_K       4787712u
#define OFF_V       8982016u
#define OFF_O       13176320u
// total = 17370624 floats = 69.5 MB

// ---------------- prep: style = w @ mod_w + 1 ----------------
__global__ void k_style(const float* __restrict__ w, const float* __restrict__ mod_w,
                        float* __restrict__ style) {
    int n = blockIdx.x;          // 8
    int c = threadIdx.x;         // 256
    float acc = 0.f;
    #pragma unroll 8
    for (int e = 0; e < EE; ++e)
        acc += w[n * EE + e] * mod_w[e * CC + c];
    style[n * CC + c] = acc + 1.0f;
}

// ------------- prep: Wq' = mp_weight(qkv_w)*gain, bias' = b*gain -------------
__global__ void k_prep_wq(const float* __restrict__ qkv_w, const float* __restrict__ gain,
                          const float* __restrict__ bias, float* __restrict__ wq,
                          float* __restrict__ biasg) {
    int o = blockIdx.x;          // 1536
    int t = threadIdx.x;         // 256
    __shared__ float red[256];
    float val = qkv_w[o * CC + t];
    red[t] = val;
    __syncthreads();
    for (int s = 128; s > 0; s >>= 1) { if (t < s) red[t] += red[t + s]; __syncthreads(); }
    float mean = red[0] * (1.0f / 256.0f);
    __syncthreads();
    float cv = val - mean;
    red[t] = cv * cv;
    __syncthreads();
    for (int s = 128; s > 0; s >>= 1) { if (t < s) red[t] += red[t + s]; __syncthreads(); }
    float norm = sqrtf(red[0]) + 1e-8f;
    float g = gain[o];
    wq[o * CC + t] = cv / norm * (1.0f / 16.0f) * g;   // /sqrt(256)=16
    if (t == 0) biasg[o] = bias[o] * g;
}

// ------------- prep: Wp' = mp_weight(proj_w)*ResidualGain -------------
__global__ void k_prep_wp(const float* __restrict__ proj_w, const float* __restrict__ rgain,
                          float* __restrict__ wp) {
    int r = blockIdx.x;          // 256
    int t = threadIdx.x;         // 256, 2 elems each (512 cols)
    __shared__ float red[256];
    float v0 = proj_w[r * 512 + t];
    float v1 = proj_w[r * 512 + 256 + t];
    red[t] = v0 + v1;
    __syncthreads();
    for (int s = 128; s > 0; s >>= 1) { if (t < s) red[t] += red[t + s]; __syncthreads(); }
    float mean = red[0] * (1.0f / 512.0f);
    __syncthreads();
    float c0 = v0 - mean, c1 = v1 - mean;
    red[t] = c0 * c0 + c1 * c1;
    __syncthreads();
    for (int s = 128; s > 0; s >>= 1) { if (t < s) red[t] += red[t + s]; __syncthreads(); }
    float norm = sqrtf(red[0]) + 1e-8f;
    float scale = rgain[r] / (norm * sqrtf(512.0f));
    wp[r * 512 + t] = c0 * scale;
    wp[r * 512 + 256 + t] = c1 * scale;
}

// ------------- prep: rope tables (1024 x 32) -------------
__global__ void k_rope(float* __restrict__ cosT, float* __restrict__ sinT) {
    int l = blockIdx.x * 256 + threadIdx.x;   // 4 blocks x 256
    if (l >= LL) return;
    int hh = l >> 5, ww = l & 31;
    float lg = logf(10000.0f);
    #pragma unroll
    for (int j = 0; j < 16; ++j) {
        float f = expf(-(float)j * (1.0f / 16.0f) * lg);
        float a1 = (float)hh * f;
        float a2 = (float)ww * f;
        cosT[l * 32 + j]      = cosf(a1);
        sinT[l * 32 + j]      = sinf(a1);
        cosT[l * 32 + 16 + j] = cosf(a2);
        sinT[l * 32 + 16 + j] = sinf(a2);
    }
}

// ------------- QKV GEMM (64x64 tile) + fused bias/rope/l2norm epilogue -------------
__global__ __launch_bounds__(256) void k_qkv(const float* __restrict__ x,
                                             const float* __restrict__ style,
                                             const float* __restrict__ wq,
                                             const float* __restrict__ biasg,
                                             const float* __restrict__ cosT,
                                             const float* __restrict__ sinT,
                                             float* __restrict__ qb, float* __restrict__ kb,
                                             float* __restrict__ vb) {
    int lb = blockIdx.x;              // 16  (l blocks of 64)
    int ph = blockIdx.y;              // 24  (part*8 + h)
    int n  = blockIdx.z;              // 8
    int part = ph >> 3, h = ph & 7;
    int o0 = part * 512 + h * 64;
    int l0 = lb * 64;
    __shared__ float As[64][65];
    __shared__ float Xs[64][65];
    int t = threadIdx.x;
    int ty = t >> 4, tx = t & 15;
    float acc[4][4] = {};
    for (int kt = 0; kt < CC; kt += 64) {
        #pragma unroll
        for (int i = 0; i < 16; ++i) {
            int idx = t + i * 256;
            int r = idx >> 6, cc = idx & 63;
            As[r][cc] = wq[(o0 + r) * CC + kt + cc];
        }
        #pragma unroll
        for (int i = 0; i < 16; ++i) {
            int idx = t + i * 256;
            int c = idx >> 6, l = idx & 63;
            Xs[c][l] = x[n * (CC * LL) + (kt + c) * LL + l0 + l] * style[n * CC + kt + c];
        }
        __syncthreads();
        #pragma unroll 16
        for (int kk = 0; kk < 64; ++kk) {
            float a[4], b[4];
            #pragma unroll
            for (int i = 0; i < 4; ++i) a[i] = As[ty * 4 + i][kk];
            #pragma unroll
            for (int j = 0; j < 4; ++j) b[j] = Xs[kk][tx * 4 + j];
            #pragma unroll
            for (int i = 0; i < 4; ++i)
                #pragma unroll
                for (int j = 0; j < 4; ++j)
                    acc[i][j] += a[i] * b[j];
        }
        __syncthreads();
    }
    // stage y tile (d x l) back into As, with bias
    #pragma unroll
    for (int i = 0; i < 4; ++i)
        #pragma unroll
        for (int j = 0; j < 4; ++j)
            As[ty * 4 + i][tx * 4 + j] = acc[i][j] + biasg[o0 + ty * 4 + i];
    __syncthreads();

    if (part == 2) {
        // v: plain transpose store (n,h,l,d)
        #pragma unroll
        for (int i = 0; i < 16; ++i) {
            int idx = t + i * 256;
            int l = idx >> 6, d = idx & 63;
            vb[((size_t)(n * 8 + h) * LL + l0 + l) * DH + d] = As[d][l];
        }
    } else {
        float* dst = (part == 0) ? qb : kb;
        if (t < 64) {
            int l = l0 + t;
            float r[64];
            float ss = 0.f;
            #pragma unroll
            for (int j = 0; j < 32; ++j) {
                float cth = cosT[l * 32 + j], sth = sinT[l * 32 + j];
                float x1 = As[2 * j][t], x2 = As[2 * j + 1][t];
                float r1 = x1 * cth - x2 * sth;
                float r2 = x1 * sth + x2 * cth;
                r[2 * j] = r1; r[2 * j + 1] = r2;
                ss += r1 * r1 + r2 * r2;
            }
            float inv = 1.0f / (sqrtf(ss) + 1e-8f);
            float* p = dst + ((size_t)(n * 8 + h) * LL + l) * DH;
            #pragma unroll
            for (int d = 0; d < 64; ++d) p[d] = r[d] * inv;
        }
    }
}

// ------------- attention: 1 thread = 1 query row, fixed shift m -------------
__global__ __launch_bounds__(256) void k_attn(const float* __restrict__ qb,
                                              const float* __restrict__ kb,
                                              const float* __restrict__ vb,
                                              const float* __restrict__ sinks,
                                              float* __restrict__ ob) {
    int lb = blockIdx.x;   // 4
    int h  = blockIdx.y;   // 8
    int n  = blockIdx.z;   // 8
    int t  = threadIdx.x;  // 256
    int l  = lb * 256 + t;
    const size_t headoff = (size_t)(n * 8 + h) * LL * DH;
    const float4* q4 = (const float4*)(qb + headoff + (size_t)l * DH);
    float4 qr[16];
    #pragma unroll
    for (int i = 0; i < 16; ++i) qr[i] = q4[i];

    float snk = sinks[h];
    float m = fmaxf(8.0f, snk);
    float s = __expf(snk - m);
    float4 oacc[16];
    #pragma unroll
    for (int i = 0; i < 16; ++i) oacc[i] = make_float4(0.f, 0.f, 0.f, 0.f);

    __shared__ float ks[64][64];
    __shared__ float vs[64][64];

    for (int kt = 0; kt < LL; kt += 64) {
        const float4* kg = (const float4*)(kb + headoff + (size_t)kt * DH);
        const float4* vg = (const float4*)(vb + headoff + (size_t)kt * DH);
        float4* ks4 = (float4*)&ks[0][0];
        float4* vs4 = (float4*)&vs[0][0];
        #pragma unroll
        for (int i = 0; i < 4; ++i) {
            ks4[t + i * 256] = kg[t + i * 256];
            vs4[t + i * 256] = vg[t + i * 256];
        }
        __syncthreads();
        #pragma unroll 4
        for (int kv = 0; kv < 64; ++kv) {
            const float4* kr = (const float4*)&ks[kv][0];
            float d0 = 0.f, d1 = 0.f, d2 = 0.f, d3 = 0.f;
            #pragma unroll
            for (int i = 0; i < 16; i += 4) {
                float4 k0 = kr[i], k1 = kr[i + 1], k2 = kr[i + 2], k3 = kr[i + 3];
                d0 += qr[i].x * k0.x + qr[i].y * k0.y + qr[i].z * k0.z + qr[i].w * k0.w;
                d1 += qr[i+1].x * k1.x + qr[i+1].y * k1.y + qr[i+1].z * k1.z + qr[i+1].w * k1.w;
                d2 += qr[i+2].x * k2.x + qr[i+2].y * k2.y + qr[i+2].z * k2.z + qr[i+2].w * k2.w;
                d3 += qr[i+3].x * k3.x + qr[i+3].y * k3.y + qr[i+3].z * k3.z + qr[i+3].w * k3.w;
            }
            float p = __expf(8.0f * (d0 + d1 + d2 + d3) - m);
            s += p;
            const float4* vr = (const float4*)&vs[kv][0];
            #pragma unroll
            for (int i = 0; i < 16; ++i) {
                float4 vv = vr[i];
                oacc[i].x += p * vv.x; oacc[i].y += p * vv.y;
                oacc[i].z += p * vv.z; oacc[i].w += p * vv.w;
            }
        }
        __syncthreads();
    }
    float inv = 1.0f / s;
    float4* o4 = (float4*)(ob + headoff + (size_t)l * DH);
    #pragma unroll
    for (int i = 0; i < 16; ++i) {
        float4 vv = oacc[i];
        o4[i] = make_float4(vv.x * inv, vv.y * inv, vv.z * inv, vv.w * inv);
    }
}

// ------------- output projection (64x64 tile) + residual -------------
__global__ __launch_bounds__(256) void k_proj(const float* __restrict__ ob,
                                              const float* __restrict__ wp,
                                              const float* __restrict__ x,
                                              float* __restrict__ out) {
    int lb = blockIdx.x;   // 16
    int cb = blockIdx.y;   // 4
    int n  = blockIdx.z;   // 8
    int c0 = cb * 64;
    int l0 = lb * 64;
    __shared__ float As[64][65];
    __shared__ float Bs[64][65];
    int t = threadIdx.x;
    int ty = t >> 4, tx = t & 15;
    float acc[4][4] = {};
    for (int h = 0; h < 8; ++h) {   // K chunks of 64 (one head each)
        #pragma unroll
        for (int i = 0; i < 16; ++i) {
            int idx = t + i * 256;
            int r = idx >> 6, cc = idx & 63;
            As[r][cc] = wp[(c0 + r) * 512 + h * 64 + cc];
        }
        #pragma unroll
        for (int i = 0; i < 16; ++i) {
            int idx = t + i * 256;
            int l = idx >> 6, d = idx & 63;
            Bs[d][l] = ob[((size_t)(n * 8 + h) * LL + l0 + l) * DH + d];
        }
        __syncthreads();
        #pragma unroll 16
        for (int kk = 0; kk < 64; ++kk) {
            float a[4], b[4];
            #pragma unroll
            for (int i = 0; i < 4; ++i) a[i] = As[ty * 4 + i][kk];
            #pragma unroll
            for (int j = 0; j < 4; ++j) b[j] = Bs[kk][tx * 4 + j];
            #pragma unroll
            for (int i = 0; i < 4; ++i)
                #pragma unroll
                for (int j = 0; j < 4; ++j)
                    acc[i][j] += a[i] * b[j];
        }
        __syncthreads();
    }
    #pragma unroll
    for (int i = 0; i < 4; ++i) {
        int c = c0 + ty * 4 + i;
        #pragma unroll
        for (int j = 0; j < 4; ++j) {
            int l = l0 + tx * 4 + j;
            size_t idx = (size_t)n * (CC * LL) + (size_t)c * LL + l;
            out[idx] = x[idx] + acc[i][j];
        }
    }
}

extern "C" void kernel_launch(void* const* d_in, const int* in_sizes, int n_in,
                              void* d_out, int out_size, void* d_ws, size_t ws_size,
                              hipStream_t stream) {
    const float* x       = (const float*)d_in[0];
    const float* w       = (const float*)d_in[1];
    const float* igain   = (const float*)d_in[2];
    const float* rgain   = (const float*)d_in[3];
    const float* qkv_w   = (const float*)d_in[4];
    const float* qkv_b   = (const float*)d_in[5];
    const float* mod_w   = (const float*)d_in[6];
    const float* proj_w  = (const float*)d_in[7];
    const float* sinks   = (const float*)d_in[8];
    float* out = (float*)d_out;
    float* ws  = (float*)d_ws;

    float* style = ws + OFF_STYLE;
    float* wq    = ws + OFF_WQ;
    float* biasg = ws + OFF_BIAS;
    float* wp    = ws + OFF_WP;
    float* cosT  = ws + OFF_COS;
    float* sinT  = ws + OFF_SIN;
    float* qb    = ws + OFF_Q;
    float* kb    = ws + OFF_K;
    float* vb    = ws + OFF_V;
    float* ob    = ws + OFF_O;

    k_style<<<NN, 256, 0, stream>>>(w, mod_w, style);
    k_prep_wq<<<1536, 256, 0, stream>>>(qkv_w, igain, qkv_b, wq, biasg);
    k_prep_wp<<<256, 256, 0, stream>>>(proj_w, rgain, wp);
    k_rope<<<4, 256, 0, stream>>>(cosT, sinT);
    k_qkv<<<dim3(16, 24, NN), 256, 0, stream>>>(x, style, wq, biasg, cosT, sinT, qb, kb, vb);
    k_attn<<<dim3(4, HEADS, NN), 256, 0, stream>>>(qb, kb, vb, sinks, ob);
    k_proj<<<dim3(16, 4, NN), 256, 0, stream>>>(ob, wp, x, out);
}

// Round 3
// 379.964 us; speedup vs baseline: 2.6060x; 2.6060x over previous
//
#include <hip/hip_runtime.h>
#include <hip/hip_bf16.h>
#include <math.h>

// Problem constants
#define NN 8
#define CC 256
#define LL 1024
#define EE 512
#define HEADS 8
#define DH 64

// Workspace float offsets
#define OFF_STYLE   0u          // 8*256            = 2048
#define OFF_WQ      2048u       // 1536*256         = 393216
#define OFF_BIAS    395264u     // 1536
#define OFF_WP      396800u     // 256*512          = 131072
#define OFF_COS     527872u     // 1024*32          = 32768
#define OFF_SIN     560640u     // 1024*32          = 32768
#define OFF_Q       593408u     // bf16 64*1024*64  = 2097152 floats
#define OFF_K       2690560u    // bf16
#define OFF_V       4787712u    // bf16 (transposed [d][l])
#define OFF_O       6884864u    // fp32 4194304
// total = 11079168 floats = 44.3 MB

typedef __bf16 bf16x8 __attribute__((ext_vector_type(8)));
typedef float f32x4 __attribute__((ext_vector_type(4)));

// ---------------- prep: style = w @ mod_w + 1 ----------------
__global__ void k_style(const float* __restrict__ w, const float* __restrict__ mod_w,
                        float* __restrict__ style) {
    int n = blockIdx.x;          // 8
    int c = threadIdx.x;         // 256
    float acc = 0.f;
    #pragma unroll 8
    for (int e = 0; e < EE; ++e)
        acc += w[n * EE + e] * mod_w[e * CC + c];
    style[n * CC + c] = acc + 1.0f;
}

// ------------- prep: Wq' = mp_weight(qkv_w)*gain, bias' = b*gain -------------
__global__ void k_prep_wq(const float* __restrict__ qkv_w, const float* __restrict__ gain,
                          const float* __restrict__ bias, float* __restrict__ wq,
                          float* __restrict__ biasg) {
    int o = blockIdx.x;          // 1536
    int t = threadIdx.x;         // 256
    __shared__ float red[256];
    float val = qkv_w[o * CC + t];
    red[t] = val;
    __syncthreads();
    for (int s = 128; s > 0; s >>= 1) { if (t < s) red[t] += red[t + s]; __syncthreads(); }
    float mean = red[0] * (1.0f / 256.0f);
    __syncthreads();
    float cv = val - mean;
    red[t] = cv * cv;
    __syncthreads();
    for (int s = 128; s > 0; s >>= 1) { if (t < s) red[t] += red[t + s]; __syncthreads(); }
    float norm = sqrtf(red[0]) + 1e-8f;
    float g = gain[o];
    wq[o * CC + t] = cv / norm * (1.0f / 16.0f) * g;   // /sqrt(256)=16
    if (t == 0) biasg[o] = bias[o] * g;
}

// ------------- prep: Wp' = mp_weight(proj_w)*ResidualGain -------------
__global__ void k_prep_wp(const float* __restrict__ proj_w, const float* __restrict__ rgain,
                          float* __restrict__ wp) {
    int r = blockIdx.x;          // 256
    int t = threadIdx.x;         // 256, 2 elems each (512 cols)
    __shared__ float red[256];
    float v0 = proj_w[r * 512 + t];
    float v1 = proj_w[r * 512 + 256 + t];
    red[t] = v0 + v1;
    __syncthreads();
    for (int s = 128; s > 0; s >>= 1) { if (t < s) red[t] += red[t + s]; __syncthreads(); }
    float mean = red[0] * (1.0f / 512.0f);
    __syncthreads();
    float c0 = v0 - mean, c1 = v1 - mean;
    red[t] = c0 * c0 + c1 * c1;
    __syncthreads();
    for (int s = 128; s > 0; s >>= 1) { if (t < s) red[t] += red[t + s]; __syncthreads(); }
    float norm = sqrtf(red[0]) + 1e-8f;
    float scale = rgain[r] / (norm * sqrtf(512.0f));
    wp[r * 512 + t] = c0 * scale;
    wp[r * 512 + 256 + t] = c1 * scale;
}

// ------------- prep: rope tables (1024 x 32) -------------
__global__ void k_rope(float* __restrict__ cosT, float* __restrict__ sinT) {
    int l = blockIdx.x * 256 + threadIdx.x;   // 4 blocks x 256
    if (l >= LL) return;
    int hh = l >> 5, ww = l & 31;
    float lg = logf(10000.0f);
    #pragma unroll
    for (int j = 0; j < 16; ++j) {
        float f = expf(-(float)j * (1.0f / 16.0f) * lg);
        float a1 = (float)hh * f;
        float a2 = (float)ww * f;
        cosT[l * 32 + j]      = cosf(a1);
        sinT[l * 32 + j]      = sinf(a1);
        cosT[l * 32 + 16 + j] = cosf(a2);
        sinT[l * 32 + 16 + j] = sinf(a2);
    }
}

// ------------- QKV GEMM (64x64 tile) + fused bias/rope/l2norm epilogue -------------
// q,k stored bf16 row-major [head][l][64]; v stored bf16 transposed [head][d][1024]
__global__ __launch_bounds__(256) void k_qkv(const float* __restrict__ x,
                                             const float* __restrict__ style,
                                             const float* __restrict__ wq,
                                             const float* __restrict__ biasg,
                                             const float* __restrict__ cosT,
                                             const float* __restrict__ sinT,
                                             __hip_bfloat16* __restrict__ qb,
                                             __hip_bfloat16* __restrict__ kb,
                                             __hip_bfloat16* __restrict__ vt) {
    int lb = blockIdx.x;              // 16  (l blocks of 64)
    int ph = blockIdx.y;              // 24  (part*8 + h)
    int n  = blockIdx.z;              // 8
    int part = ph >> 3, h = ph & 7;
    int o0 = part * 512 + h * 64;
    int l0 = lb * 64;
    __shared__ float As[64][65];
    __shared__ float Xs[64][65];
    int t = threadIdx.x;
    int ty = t >> 4, tx = t & 15;
    float acc[4][4] = {};
    for (int kt = 0; kt < CC; kt += 64) {
        #pragma unroll
        for (int i = 0; i < 16; ++i) {
            int idx = t + i * 256;
            int r = idx >> 6, cc = idx & 63;
            As[r][cc] = wq[(o0 + r) * CC + kt + cc];
        }
        #pragma unroll
        for (int i = 0; i < 16; ++i) {
            int idx = t + i * 256;
            int c = idx >> 6, l = idx & 63;
            Xs[c][l] = x[n * (CC * LL) + (kt + c) * LL + l0 + l] * style[n * CC + kt + c];
        }
        __syncthreads();
        #pragma unroll 16
        for (int kk = 0; kk < 64; ++kk) {
            float a[4], b[4];
            #pragma unroll
            for (int i = 0; i < 4; ++i) a[i] = As[ty * 4 + i][kk];
            #pragma unroll
            for (int j = 0; j < 4; ++j) b[j] = Xs[kk][tx * 4 + j];
            #pragma unroll
            for (int i = 0; i < 4; ++i)
                #pragma unroll
                for (int j = 0; j < 4; ++j)
                    acc[i][j] += a[i] * b[j];
        }
        __syncthreads();
    }
    // stage y tile (d x l) back into As, with bias
    #pragma unroll
    for (int i = 0; i < 4; ++i)
        #pragma unroll
        for (int j = 0; j < 4; ++j)
            As[ty * 4 + i][tx * 4 + j] = acc[i][j] + biasg[o0 + ty * 4 + i];
    __syncthreads();

    if (part == 2) {
        // v: bf16 transposed store [head][d][l]
        #pragma unroll
        for (int i = 0; i < 16; ++i) {
            int idx = t + i * 256;
            int d = idx >> 6, l = idx & 63;
            vt[((size_t)(n * 8 + h) * DH + d) * LL + l0 + l] = __float2bfloat16(As[d][l]);
        }
    } else {
        __hip_bfloat16* dst = (part == 0) ? qb : kb;
        if (t < 64) {
            int l = l0 + t;
            float r[64];
            float ss = 0.f;
            #pragma unroll
            for (int j = 0; j < 32; ++j) {
                float cth = cosT[l * 32 + j], sth = sinT[l * 32 + j];
                float x1 = As[2 * j][t], x2 = As[2 * j + 1][t];
                float r1 = x1 * cth - x2 * sth;
                float r2 = x1 * sth + x2 * cth;
                r[2 * j] = r1; r[2 * j + 1] = r2;
                ss += r1 * r1 + r2 * r2;
            }
            float inv = 1.0f / (sqrtf(ss) + 1e-8f);
            __hip_bfloat16* p = dst + ((size_t)(n * 8 + h) * LL + l) * DH;
            #pragma unroll
            for (int d = 0; d < 64; ++d) p[d] = __float2bfloat16(r[d] * inv);
        }
    }
}

// ------------- MFMA flash attention (fixed softmax shift, no rescale) -------------
// 4 waves/block, each wave owns 32 q rows; KV tiles of 64.
__global__ __launch_bounds__(256) void k_attn_mfma(
    const __hip_bfloat16* __restrict__ qb, const __hip_bfloat16* __restrict__ kb,
    const __hip_bfloat16* __restrict__ vt, const float* __restrict__ sinks,
    float* __restrict__ ob) {
    int qblk = blockIdx.x;   // 8 (q blocks of 128)
    int h    = blockIdx.y;   // 8
    int n    = blockIdx.z;   // 8
    int tid  = threadIdx.x;
    int wid  = tid >> 6, lane = tid & 63;
    int g = lane >> 4, r16 = lane & 15;

    size_t head = (size_t)(n * 8 + h);
    const __hip_bfloat16* Q = qb + head * (size_t)(LL * DH);
    const __hip_bfloat16* K = kb + head * (size_t)(LL * DH);
    const __hip_bfloat16* V = vt + head * (size_t)(DH * LL);   // [d][l]
    float* O = ob + head * (size_t)(LL * DH);

    int q0 = qblk * 128 + wid * 32;

    // per-wave P staging buffer: 32 rows x 72 (pad) bf16 = 4608 B
    __shared__ __hip_bfloat16 pls[4][32][72];

    // Q fragments: lane holds row (lane&15), d = 32*dc + 8*g .. +7
    bf16x8 qf[2][2];
    #pragma unroll
    for (int qm = 0; qm < 2; ++qm)
        #pragma unroll
        for (int dc = 0; dc < 2; ++dc)
            qf[qm][dc] = *reinterpret_cast<const bf16x8*>(
                Q + (size_t)(q0 + qm * 16 + r16) * DH + dc * 32 + g * 8);

    float snk = sinks[h];
    float m = fmaxf(8.0f, snk);
    const float c1 = 8.0f * 1.44269504f;
    const float c0 = -m * 1.44269504f;

    f32x4 oacc[2][4];
    #pragma unroll
    for (int qm = 0; qm < 2; ++qm)
        #pragma unroll
        for (int dn = 0; dn < 4; ++dn)
            oacc[qm][dn] = (f32x4){0.f, 0.f, 0.f, 0.f};
    f32x4 ssum[2];
    ssum[0] = (f32x4){0.f, 0.f, 0.f, 0.f};
    ssum[1] = (f32x4){0.f, 0.f, 0.f, 0.f};

    for (int kt = 0; kt < LL; kt += 64) {
        // ---- S = Q K^T over 64 k rows ----
        f32x4 sacc[2][4];
        #pragma unroll
        for (int qm = 0; qm < 2; ++qm)
            #pragma unroll
            for (int kn = 0; kn < 4; ++kn)
                sacc[qm][kn] = (f32x4){0.f, 0.f, 0.f, 0.f};
        #pragma unroll
        for (int kn = 0; kn < 4; ++kn) {
            #pragma unroll
            for (int dc = 0; dc < 2; ++dc) {
                bf16x8 kf = *reinterpret_cast<const bf16x8*>(
                    K + (size_t)(kt + kn * 16 + r16) * DH + dc * 32 + g * 8);
                #pragma unroll
                for (int qm = 0; qm < 2; ++qm)
                    sacc[qm][kn] = __builtin_amdgcn_mfma_f32_16x16x32_bf16(
                        qf[qm][dc], kf, sacc[qm][kn], 0, 0, 0);
            }
        }
        // ---- P = exp(8S - m); accumulate row sums; stage P to LDS ----
        #pragma unroll
        for (int qm = 0; qm < 2; ++qm)
            #pragma unroll
            for (int kn = 0; kn < 4; ++kn)
                #pragma unroll
                for (int reg = 0; reg < 4; ++reg) {
                    float p = exp2f(fmaf(sacc[qm][kn][reg], c1, c0));
                    ssum[qm][reg] += p;
                    pls[wid][qm * 16 + 4 * g + reg][kn * 16 + r16] = __float2bfloat16(p);
                }
        // ---- O += P V  (A-frag of P from LDS, B-frag of V from global) ----
        #pragma unroll
        for (int kc = 0; kc < 2; ++kc) {
            bf16x8 pa0 = *reinterpret_cast<const bf16x8*>(&pls[wid][r16][kc * 32 + g * 8]);
            bf16x8 pa1 = *reinterpret_cast<const bf16x8*>(&pls[wid][16 + r16][kc * 32 + g * 8]);
            #pragma unroll
            for (int dn = 0; dn < 4; ++dn) {
                bf16x8 vf = *reinterpret_cast<const bf16x8*>(
                    V + (size_t)(dn * 16 + r16) * LL + kt + kc * 32 + g * 8);
                oacc[0][dn] = __builtin_amdgcn_mfma_f32_16x16x32_bf16(pa0, vf, oacc[0][dn], 0, 0, 0);
                oacc[1][dn] = __builtin_amdgcn_mfma_f32_16x16x32_bf16(pa1, vf, oacc[1][dn], 0, 0, 0);
            }
        }
    }

    // ---- finish: row sums via 16-lane butterfly, scale, store ----
    float sink_e = exp2f((snk - m) * 1.44269504f);
    #pragma unroll
    for (int qm = 0; qm < 2; ++qm) {
        #pragma unroll
        for (int reg = 0; reg < 4; ++reg) {
            float s = ssum[qm][reg];
            s += __shfl_xor(s, 1);
            s += __shfl_xor(s, 2);
            s += __shfl_xor(s, 4);
            s += __shfl_xor(s, 8);
            float inv = 1.0f / (s + sink_e);
            #pragma unroll
            for (int dn = 0; dn < 4; ++dn)
                O[(size_t)(q0 + qm * 16 + 4 * g + reg) * DH + dn * 16 + r16] =
                    oacc[qm][dn][reg] * inv;
        }
    }
}

// ------------- output projection (64x64 tile) + residual -------------
__global__ __launch_bounds__(256) void k_proj(const float* __restrict__ ob,
                                              const float* __restrict__ wp,
                                              const float* __restrict__ x,
                                              float* __restrict__ out) {
    int lb = blockIdx.x;   // 16
    int cb = blockIdx.y;   // 4
    int n  = blockIdx.z;   // 8
    int c0 = cb * 64;
    int l0 = lb * 64;
    __shared__ float As[64][65];
    __shared__ float Bs[64][65];
    int t = threadIdx.x;
    int ty = t >> 4, tx = t & 15;
    float acc[4][4] = {};
    for (int h = 0; h < 8; ++h) {   // K chunks of 64 (one head each)
        #pragma unroll
        for (int i = 0; i < 16; ++i) {
            int idx = t + i * 256;
            int r = idx >> 6, cc = idx & 63;
            As[r][cc] = wp[(c0 + r) * 512 + h * 64 + cc];
        }
        #pragma unroll
        for (int i = 0; i < 16; ++i) {
            int idx = t + i * 256;
            int l = idx >> 6, d = idx & 63;
            Bs[d][l] = ob[((size_t)(n * 8 + h) * LL + l0 + l) * DH + d];
        }
        __syncthreads();
        #pragma unroll 16
        for (int kk = 0; kk < 64; ++kk) {
            float a[4], b[4];
            #pragma unroll
            for (int i = 0; i < 4; ++i) a[i] = As[ty * 4 + i][kk];
            #pragma unroll
            for (int j = 0; j < 4; ++j) b[j] = Bs[kk][tx * 4 + j];
            #pragma unroll
            for (int i = 0; i < 4; ++i)
                #pragma unroll
                for (int j = 0; j < 4; ++j)
                    acc[i][j] += a[i] * b[j];
        }
        __syncthreads();
    }
    #pragma unroll
    for (int i = 0; i < 4; ++i) {
        int c = c0 + ty * 4 + i;
        #pragma unroll
        for (int j = 0; j < 4; ++j) {
            int l = l0 + tx * 4 + j;
            size_t idx = (size_t)n * (CC * LL) + (size_t)c * LL + l;
            out[idx] = x[idx] + acc[i][j];
        }
    }
}

extern "C" void kernel_launch(void* const* d_in, const int* in_sizes, int n_in,
                              void* d_out, int out_size, void* d_ws, size_t ws_size,
                              hipStream_t stream) {
    const float* x       = (const float*)d_in[0];
    const float* w       = (const float*)d_in[1];
    const float* igain   = (const float*)d_in[2];
    const float* rgain   = (const float*)d_in[3];
    const float* qkv_w   = (const float*)d_in[4];
    const float* qkv_b   = (const float*)d_in[5];
    const float* mod_w   = (const float*)d_in[6];
    const float* proj_w  = (const float*)d_in[7];
    const float* sinks   = (const float*)d_in[8];
    float* out = (float*)d_out;
    float* ws  = (float*)d_ws;

    float* style = ws + OFF_STYLE;
    float* wq    = ws + OFF_WQ;
    float* biasg = ws + OFF_BIAS;
    float* wp    = ws + OFF_WP;
    float* cosT  = ws + OFF_COS;
    float* sinT  = ws + OFF_SIN;
    __hip_bfloat16* qb = (__hip_bfloat16*)(ws + OFF_Q);
    __hip_bfloat16* kb = (__hip_bfloat16*)(ws + OFF_K);
    __hip_bfloat16* vt = (__hip_bfloat16*)(ws + OFF_V);
    float* obuf = ws + OFF_O;

    k_style<<<NN, 256, 0, stream>>>(w, mod_w, style);
    k_prep_wq<<<1536, 256, 0, stream>>>(qkv_w, igain, qkv_b, wq, biasg);
    k_prep_wp<<<256, 256, 0, stream>>>(proj_w, rgain, wp);
    k_rope<<<4, 256, 0, stream>>>(cosT, sinT);
    k_qkv<<<dim3(16, 24, NN), 256, 0, stream>>>(x, style, wq, biasg, cosT, sinT, qb, kb, vt);
    k_attn_mfma<<<dim3(8, HEADS, NN), 256, 0, stream>>>(qb, kb, vt, sinks, obuf);
    k_proj<<<dim3(16, 4, NN), 256, 0, stream>>>(obuf, wp, x, out);
}

// Round 5
// 188.526 us; speedup vs baseline: 5.2522x; 2.0154x over previous
//
#include <hip/hip_runtime.h>
#include <hip/hip_bf16.h>
#include <math.h>

// Problem constants
#define NN 8
#define CC 256
#define LL 1024
#define EE 512
#define HEADS 8
#define DH 64

// Workspace float offsets
#define OFF_STYLE   0u          // 2048
#define OFF_BIAS    2048u       // 1536
#define OFF_COS     3584u       // 32768
#define OFF_SIN     36352u      // 32768
#define OFF_WQB     69120u      // bf16 1536*256 -> 196608 floats
#define OFF_WPB     265728u     // bf16 256*512  -> 65536 floats
#define OFF_XMT     331264u     // bf16 8*1024*256 -> 1048576 floats
#define OFF_Q       1379840u    // bf16 64*1024*64 -> 2097152 floats
#define OFF_K       3476992u
#define OFF_V       5574144u    // bf16 transposed [head][d][l]
#define OFF_O       7671296u    // bf16 [n][l][512] -> 2097152 floats
// total 9768448 floats = 39.1 MB

typedef __bf16 bf16x8 __attribute__((ext_vector_type(8)));
typedef float f32x4 __attribute__((ext_vector_type(4)));

// ---------------- prep: style = w @ mod_w + 1 ----------------
__global__ void k_style(const float* __restrict__ w, const float* __restrict__ mod_w,
                        float* __restrict__ style) {
    int n = blockIdx.x;          // 8
    int c = threadIdx.x;         // 256
    float acc = 0.f;
    #pragma unroll 8
    for (int e = 0; e < EE; ++e)
        acc += w[n * EE + e] * mod_w[e * CC + c];
    style[n * CC + c] = acc + 1.0f;
}

// ------------- prep: Wq' = mp_weight(qkv_w)*gain (bf16), bias' = b*gain -------------
__global__ void k_prep_wq(const float* __restrict__ qkv_w, const float* __restrict__ gain,
                          const float* __restrict__ bias, __hip_bfloat16* __restrict__ wqb,
                          float* __restrict__ biasg) {
    int o = blockIdx.x;          // 1536
    int t = threadIdx.x;         // 256
    __shared__ float red[256];
    float val = qkv_w[o * CC + t];
    red[t] = val;
    __syncthreads();
    for (int s = 128; s > 0; s >>= 1) { if (t < s) red[t] += red[t + s]; __syncthreads(); }
    float mean = red[0] * (1.0f / 256.0f);
    __syncthreads();
    float cv = val - mean;
    red[t] = cv * cv;
    __syncthreads();
    for (int s = 128; s > 0; s >>= 1) { if (t < s) red[t] += red[t + s]; __syncthreads(); }
    float norm = sqrtf(red[0]) + 1e-8f;
    float g = gain[o];
    wqb[o * CC + t] = __float2bfloat16(cv / norm * (1.0f / 16.0f) * g);
    if (t == 0) biasg[o] = bias[o] * g;
}

// ------------- prep: Wp' = mp_weight(proj_w)*ResidualGain (bf16) -------------
__global__ void k_prep_wp(const float* __restrict__ proj_w, const float* __restrict__ rgain,
                          __hip_bfloat16* __restrict__ wpb) {
    int r = blockIdx.x;          // 256
    int t = threadIdx.x;         // 256, 2 elems each
    __shared__ float red[256];
    float v0 = proj_w[r * 512 + t];
    float v1 = proj_w[r * 512 + 256 + t];
    red[t] = v0 + v1;
    __syncthreads();
    for (int s = 128; s > 0; s >>= 1) { if (t < s) red[t] += red[t + s]; __syncthreads(); }
    float mean = red[0] * (1.0f / 512.0f);
    __syncthreads();
    float c0 = v0 - mean, c1 = v1 - mean;
    red[t] = c0 * c0 + c1 * c1;
    __syncthreads();
    for (int s = 128; s > 0; s >>= 1) { if (t < s) red[t] += red[t + s]; __syncthreads(); }
    float norm = sqrtf(red[0]) + 1e-8f;
    float scale = rgain[r] / (norm * sqrtf(512.0f));
    wpb[r * 512 + t] = __float2bfloat16(c0 * scale);
    wpb[r * 512 + 256 + t] = __float2bfloat16(c1 * scale);
}

// ------------- prep: rope tables (1024 x 32) -------------
__global__ void k_rope(float* __restrict__ cosT, float* __restrict__ sinT) {
    int l = blockIdx.x * 256 + threadIdx.x;
    if (l >= LL) return;
    int hh = l >> 5, ww = l & 31;
    float lg = logf(10000.0f);
    #pragma unroll
    for (int j = 0; j < 16; ++j) {
        float f = expf(-(float)j * (1.0f / 16.0f) * lg);
        float a1 = (float)hh * f;
        float a2 = (float)ww * f;
        cosT[l * 32 + j]      = cosf(a1);
        sinT[l * 32 + j]      = sinf(a1);
        cosT[l * 32 + 16 + j] = cosf(a2);
        sinT[l * 32 + 16 + j] = sinf(a2);
    }
}

// ------------- prep: xmT[n][l][c] = bf16(x[n][c][l] * style[n][c]) -------------
__global__ __launch_bounds__(256) void k_xm(const float* __restrict__ x,
                                            const float* __restrict__ style,
                                            __hip_bfloat16* __restrict__ xmT) {
    int lb = blockIdx.x;   // 16
    int cb = blockIdx.y;   // 4
    int n  = blockIdx.z;   // 8
    int t = threadIdx.x;
    __shared__ float tile[64][68];
    int r = t >> 2, q = t & 3;     // r = c_local (0..63), q = l quarter
    float st = style[n * CC + cb * 64 + r];
    const float* xp = x + (size_t)n * (CC * LL) + (size_t)(cb * 64 + r) * LL + lb * 64 + q * 16;
    #pragma unroll
    for (int i = 0; i < 4; ++i) {
        float4 v = *reinterpret_cast<const float4*>(xp + i * 4);
        tile[r][q * 16 + i * 4 + 0] = v.x * st;
        tile[r][q * 16 + i * 4 + 1] = v.y * st;
        tile[r][q * 16 + i * 4 + 2] = v.z * st;
        tile[r][q * 16 + i * 4 + 3] = v.w * st;
    }
    __syncthreads();
    // r now = l_local, q = c chunk of 16
    __hip_bfloat16 outv[16];
    #pragma unroll
    for (int i = 0; i < 16; ++i)
        outv[i] = __float2bfloat16(tile[q * 16 + i][r]);
    __hip_bfloat16* dst = xmT + (size_t)n * (LL * CC) + (size_t)(lb * 64 + r) * CC + cb * 64 + q * 16;
    *reinterpret_cast<bf16x8*>(dst)     = *reinterpret_cast<bf16x8*>(&outv[0]);
    *reinterpret_cast<bf16x8*>(dst + 8) = *reinterpret_cast<bf16x8*>(&outv[8]);
}

// ------------- QKV MFMA GEMM + fused bias/rope/l2norm epilogue -------------
// C[o][l] = sum_c wqb[o][c] * xmT[n][l][c];  128x128 tile, 4 waves (2x2)
__global__ __launch_bounds__(256) void k_qkv2(const __hip_bfloat16* __restrict__ wqb,
                                              const __hip_bfloat16* __restrict__ xmT,
                                              const float* __restrict__ biasg,
                                              const float* __restrict__ cosT,
                                              const float* __restrict__ sinT,
                                              __hip_bfloat16* __restrict__ qb,
                                              __hip_bfloat16* __restrict__ kb,
                                              __hip_bfloat16* __restrict__ vt) {
    int lb = blockIdx.x;   // 8  (l blocks of 128)
    int ob = blockIdx.y;   // 12 (o blocks of 128)
    int n  = blockIdx.z;   // 8
    int tid = threadIdx.x;
    int wid = tid >> 6, lane = tid & 63;
    int wr = wid >> 1, wc = wid & 1;
    int g = lane >> 4, r16 = lane & 15;

    int o0 = ob * 128 + wr * 64;
    int l0 = lb * 128 + wc * 64;
    int part = o0 >> 9;            // 0=q 1=k 2=v
    int h = (o0 & 511) >> 6;

    __shared__ __hip_bfloat16 sw[4][64][72];

    const __hip_bfloat16* pA[4];
    const __hip_bfloat16* pB[4];
    #pragma unroll
    for (int m = 0; m < 4; ++m)
        pA[m] = wqb + (size_t)(o0 + m * 16 + r16) * CC + g * 8;
    #pragma unroll
    for (int nn = 0; nn < 4; ++nn)
        pB[nn] = xmT + (size_t)n * (LL * CC) + (size_t)(l0 + nn * 16 + r16) * CC + g * 8;

    f32x4 acc[4][4] = {};
    #pragma unroll
    for (int kk = 0; kk < 8; ++kk) {
        bf16x8 a[4], b[4];
        #pragma unroll
        for (int m = 0; m < 4; ++m) a[m] = *reinterpret_cast<const bf16x8*>(pA[m] + kk * 32);
        #pragma unroll
        for (int nn = 0; nn < 4; ++nn) b[nn] = *reinterpret_cast<const bf16x8*>(pB[nn] + kk * 32);
        #pragma unroll
        for (int m = 0; m < 4; ++m)
            #pragma unroll
            for (int nn = 0; nn < 4; ++nn)
                acc[m][nn] = __builtin_amdgcn_mfma_f32_16x16x32_bf16(a[m], b[nn], acc[m][nn], 0, 0, 0);
    }

    // bias per row (broadcast across l lanes)
    float bg[4][4];
    #pragma unroll
    for (int m = 0; m < 4; ++m)
        #pragma unroll
        for (int reg = 0; reg < 4; ++reg)
            bg[m][reg] = biasg[o0 + m * 16 + 4 * g + reg];

    size_t head = (size_t)(n * 8 + h);

    if (part < 2) {
        __hip_bfloat16* dst = (part == 0) ? qb : kb;
        #pragma unroll
        for (int nn = 0; nn < 4; ++nn) {
            int l = l0 + nn * 16 + r16;
            float rv[4][4];
            float ss = 0.f;
            #pragma unroll
            for (int m = 0; m < 4; ++m) {
                int j0 = m * 8 + g * 2;
                float cA = cosT[l * 32 + j0],     sA = sinT[l * 32 + j0];
                float cB = cosT[l * 32 + j0 + 1], sB = sinT[l * 32 + j0 + 1];
                float x0 = acc[m][nn][0] + bg[m][0];
                float x1 = acc[m][nn][1] + bg[m][1];
                float x2 = acc[m][nn][2] + bg[m][2];
                float x3 = acc[m][nn][3] + bg[m][3];
                rv[m][0] = x0 * cA - x1 * sA;
                rv[m][1] = x0 * sA + x1 * cA;
                rv[m][2] = x2 * cB - x3 * sB;
                rv[m][3] = x2 * sB + x3 * cB;
                ss += rv[m][0] * rv[m][0] + rv[m][1] * rv[m][1] +
                      rv[m][2] * rv[m][2] + rv[m][3] * rv[m][3];
            }
            ss += __shfl_xor(ss, 16);
            ss += __shfl_xor(ss, 32);
            float inv = 1.0f / (sqrtf(ss) + 1e-8f);
            #pragma unroll
            for (int m = 0; m < 4; ++m)
                #pragma unroll
                for (int reg = 0; reg < 4; ++reg)
                    sw[wid][nn * 16 + r16][m * 16 + 4 * g + reg] =
                        __float2bfloat16(rv[m][reg] * inv);
        }
        // vectorized store: q/k [head][l][d]
        #pragma unroll
        for (int it = 0; it < 8; ++it) {
            int idx = lane + it * 64;
            int ll = idx >> 3, ch = idx & 7;
            bf16x8 v = *reinterpret_cast<bf16x8*>(&sw[wid][ll][ch * 8]);
            *reinterpret_cast<bf16x8*>(dst + (head * LL + l0 + ll) * DH + ch * 8) = v;
        }
    } else {
        // v: stage [d][l], store transposed [head][d][1024]
        #pragma unroll
        for (int nn = 0; nn < 4; ++nn)
            #pragma unroll
            for (int m = 0; m < 4; ++m)
                #pragma unroll
                for (int reg = 0; reg < 4; ++reg)
                    sw[wid][m * 16 + 4 * g + reg][nn * 16 + r16] =
                        __float2bfloat16(acc[m][nn][reg] + bg[m][reg]);
        #pragma unroll
        for (int it = 0; it < 8; ++it) {
            int idx = lane + it * 64;
            int dd = idx >> 3, ch = idx & 7;
            bf16x8 v = *reinterpret_cast<bf16x8*>(&sw[wid][dd][ch * 8]);
            *reinterpret_cast<bf16x8*>(vt + (head * DH + dd) * LL + l0 + ch * 8) = v;
        }
    }
}

// ------------- MFMA flash attention (fixed softmax shift, no rescale) -------------
// O written bf16 as [n][l][h*64+d] for the projection GEMM.
__global__ __launch_bounds__(256) void k_attn_mfma(
    const __hip_bfloat16* __restrict__ qb, const __hip_bfloat16* __restrict__ kb,
    const __hip_bfloat16* __restrict__ vt, const float* __restrict__ sinks,
    __hip_bfloat16* __restrict__ ob) {
    int qblk = blockIdx.x;   // 8 (q blocks of 128)
    int h    = blockIdx.y;   // 8
    int n    = blockIdx.z;   // 8
    int tid  = threadIdx.x;
    int wid  = tid >> 6, lane = tid & 63;
    int g = lane >> 4, r16 = lane & 15;

    size_t head = (size_t)(n * 8 + h);
    const __hip_bfloat16* Q = qb + head * (size_t)(LL * DH);
    const __hip_bfloat16* K = kb + head * (size_t)(LL * DH);
    const __hip_bfloat16* V = vt + head * (size_t)(DH * LL);   // [d][l]
    __hip_bfloat16* O = ob + (size_t)n * (LL * 512) + h * 64;  // [l][512]

    int q0 = qblk * 128 + wid * 32;

    __shared__ __hip_bfloat16 pls[4][32][72];

    bf16x8 qf[2][2];
    #pragma unroll
    for (int qm = 0; qm < 2; ++qm)
        #pragma unroll
        for (int dc = 0; dc < 2; ++dc)
            qf[qm][dc] = *reinterpret_cast<const bf16x8*>(
                Q + (size_t)(q0 + qm * 16 + r16) * DH + dc * 32 + g * 8);

    float snk = sinks[h];
    float m = fmaxf(8.0f, snk);
    const float c1 = 8.0f * 1.44269504f;
    const float c0 = -m * 1.44269504f;

    f32x4 oacc[2][4];
    #pragma unroll
    for (int qm = 0; qm < 2; ++qm)
        #pragma unroll
        for (int dn = 0; dn < 4; ++dn)
            oacc[qm][dn] = (f32x4){0.f, 0.f, 0.f, 0.f};
    f32x4 ssum[2];
    ssum[0] = (f32x4){0.f, 0.f, 0.f, 0.f};
    ssum[1] = (f32x4){0.f, 0.f, 0.f, 0.f};

    for (int kt = 0; kt < LL; kt += 64) {
        f32x4 sacc[2][4];
        #pragma unroll
        for (int qm = 0; qm < 2; ++qm)
            #pragma unroll
            for (int kn = 0; kn < 4; ++kn)
                sacc[qm][kn] = (f32x4){0.f, 0.f, 0.f, 0.f};
        #pragma unroll
        for (int kn = 0; kn < 4; ++kn) {
            #pragma unroll
            for (int dc = 0; dc < 2; ++dc) {
                bf16x8 kf = *reinterpret_cast<const bf16x8*>(
                    K + (size_t)(kt + kn * 16 + r16) * DH + dc * 32 + g * 8);
                #pragma unroll
                for (int qm = 0; qm < 2; ++qm)
                    sacc[qm][kn] = __builtin_amdgcn_mfma_f32_16x16x32_bf16(
                        qf[qm][dc], kf, sacc[qm][kn], 0, 0, 0);
            }
        }
        #pragma unroll
        for (int qm = 0; qm < 2; ++qm)
            #pragma unroll
            for (int kn = 0; kn < 4; ++kn)
                #pragma unroll
                for (int reg = 0; reg < 4; ++reg) {
                    float p = exp2f(fmaf(sacc[qm][kn][reg], c1, c0));
                    ssum[qm][reg] += p;
                    pls[wid][qm * 16 + 4 * g + reg][kn * 16 + r16] = __float2bfloat16(p);
                }
        #pragma unroll
        for (int kc = 0; kc < 2; ++kc) {
            bf16x8 pa0 = *reinterpret_cast<const bf16x8*>(&pls[wid][r16][kc * 32 + g * 8]);
            bf16x8 pa1 = *reinterpret_cast<const bf16x8*>(&pls[wid][16 + r16][kc * 32 + g * 8]);
            #pragma unroll
            for (int dn = 0; dn < 4; ++dn) {
                bf16x8 vf = *reinterpret_cast<const bf16x8*>(
                    V + (size_t)(dn * 16 + r16) * LL + kt + kc * 32 + g * 8);
                oacc[0][dn] = __builtin_amdgcn_mfma_f32_16x16x32_bf16(pa0, vf, oacc[0][dn], 0, 0, 0);
                oacc[1][dn] = __builtin_amdgcn_mfma_f32_16x16x32_bf16(pa1, vf, oacc[1][dn], 0, 0, 0);
            }
        }
    }

    float sink_e = exp2f((snk - m) * 1.44269504f);
    #pragma unroll
    for (int qm = 0; qm < 2; ++qm) {
        #pragma unroll
        for (int reg = 0; reg < 4; ++reg) {
            float s = ssum[qm][reg];
            s += __shfl_xor(s, 1);
            s += __shfl_xor(s, 2);
            s += __shfl_xor(s, 4);
            s += __shfl_xor(s, 8);
            float inv = 1.0f / (s + sink_e);
            #pragma unroll
            for (int dn = 0; dn < 4; ++dn)
                O[(size_t)(q0 + qm * 16 + 4 * g + reg) * 512 + dn * 16 + r16] =
                    __float2bfloat16(oacc[qm][dn][reg] * inv);
        }
    }
}

// ------------- output projection MFMA + residual -------------
// C[c][l] = sum_hd wpb[c][hd] * ob[n][l][hd]; out = x + C
__global__ __launch_bounds__(256) void k_proj2(const __hip_bfloat16* __restrict__ wpb,
                                               const __hip_bfloat16* __restrict__ ob,
                                               const float* __restrict__ x,
                                               float* __restrict__ out) {
    int lb = blockIdx.x;   // 8  (l blocks of 128)
    int cb = blockIdx.y;   // 4  (c blocks of 64)
    int n  = blockIdx.z;   // 8
    int tid = threadIdx.x;
    int wid = tid >> 6, lane = tid & 63;
    int wr = wid >> 1, wc = wid & 1;
    int g = lane >> 4, r16 = lane & 15;

    int c0 = cb * 64 + wr * 32;
    int l0 = lb * 128 + wc * 64;

    const __hip_bfloat16* pA[2];
    const __hip_bfloat16* pB[4];
    #pragma unroll
    for (int m = 0; m < 2; ++m)
        pA[m] = wpb + (size_t)(c0 + m * 16 + r16) * 512 + g * 8;
    #pragma unroll
    for (int nn = 0; nn < 4; ++nn)
        pB[nn] = ob + (size_t)n * (LL * 512) + (size_t)(l0 + nn * 16 + r16) * 512 + g * 8;

    f32x4 acc[2][4] = {};
    #pragma unroll
    for (int kk = 0; kk < 16; ++kk) {
        bf16x8 a[2], b[4];
        #pragma unroll
        for (int m = 0; m < 2; ++m) a[m] = *reinterpret_cast<const bf16x8*>(pA[m] + kk * 32);
        #pragma unroll
        for (int nn = 0; nn < 4; ++nn) b[nn] = *reinterpret_cast<const bf16x8*>(pB[nn] + kk * 32);
        #pragma unroll
        for (int m = 0; m < 2; ++m)
            #pragma unroll
            for (int nn = 0; nn < 4; ++nn)
                acc[m][nn] = __builtin_amdgcn_mfma_f32_16x16x32_bf16(a[m], b[nn], acc[m][nn], 0, 0, 0);
    }

    #pragma unroll
    for (int m = 0; m < 2; ++m) {
        #pragma unroll
        for (int reg = 0; reg < 4; ++reg) {
            int c = c0 + m * 16 + 4 * g + reg;
            #pragma unroll
            for (int nn = 0; nn < 4; ++nn) {
                int l = l0 + nn * 16 + r16;
                size_t idx = (size_t)n * (CC * LL) + (size_t)c * LL + l;
                out[idx] = x[idx] + acc[m][nn][reg];
            }
        }
    }
}

extern "C" void kernel_launch(void* const* d_in, const int* in_sizes, int n_in,
                              void* d_out, int out_size, void* d_ws, size_t ws_size,
                              hipStream_t stream) {
    const float* x       = (const float*)d_in[0];
    const float* w       = (const float*)d_in[1];
    const float* igain   = (const float*)d_in[2];
    const float* rgain   = (const float*)d_in[3];
    const float* qkv_w   = (const float*)d_in[4];
    const float* qkv_b   = (const float*)d_in[5];
    const float* mod_w   = (const float*)d_in[6];
    const float* proj_w  = (const float*)d_in[7];
    const float* sinks   = (const float*)d_in[8];
    float* out = (float*)d_out;
    float* ws  = (float*)d_ws;

    float* style = ws + OFF_STYLE;
    float* biasg = ws + OFF_BIAS;
    float* cosT  = ws + OFF_COS;
    float* sinT  = ws + OFF_SIN;
    __hip_bfloat16* wqb = (__hip_bfloat16*)(ws + OFF_WQB);
    __hip_bfloat16* wpb = (__hip_bfloat16*)(ws + OFF_WPB);
    __hip_bfloat16* xmT = (__hip_bfloat16*)(ws + OFF_XMT);
    __hip_bfloat16* qb  = (__hip_bfloat16*)(ws + OFF_Q);
    __hip_bfloat16* kb  = (__hip_bfloat16*)(ws + OFF_K);
    __hip_bfloat16* vt  = (__hip_bfloat16*)(ws + OFF_V);
    __hip_bfloat16* obuf = (__hip_bfloat16*)(ws + OFF_O);

    k_style<<<NN, 256, 0, stream>>>(w, mod_w, style);
    k_prep_wq<<<1536, 256, 0, stream>>>(qkv_w, igain, qkv_b, wqb, biasg);
    k_prep_wp<<<256, 256, 0, stream>>>(proj_w, rgain, wpb);
    k_rope<<<4, 256, 0, stream>>>(cosT, sinT);
    k_xm<<<dim3(16, 4, NN), 256, 0, stream>>>(x, style, xmT);
    k_qkv2<<<dim3(8, 12, NN), 256, 0, stream>>>(wqb, xmT, biasg, cosT, sinT, qb, kb, vt);
    k_attn_mfma<<<dim3(8, HEADS, NN), 256, 0, stream>>>(qb, kb, vt, sinks, obuf);
    k_proj2<<<dim3(8, 4, NN), 256, 0, stream>>>(wpb, obuf, x, out);
}